// Round 4
// baseline (599.476 us; speedup 1.0000x reference)
//
#include <hip/hip_runtime.h>

// LogicGatedSNN: fused wave-per-row, zero-LDS, zero-barrier kernel.
//
// R2 post-mortem: split kernels were NEUTRAL vs fused (A+B ~= 196 us).
// Harness poison fills stream 1 GB at 6.5 TB/s on this box, so the limit
// is kernel structure, not HBM. This version: one 64-lane wave owns one
// row end-to-end. 8192 rows = 8192 waves = exactly full chip residency
// (256 CU x 32 waves). No LDS (R0's occupancy killer), no __syncthreads;
// reduction is shfl-only. Trace loads have no dependency on the reduce,
// so they overlap the shfl chain; phases overlap across resident waves.
// Nontemporal trace stores keep L3 for the read streams.
//
// R3 fix: __builtin_nontemporal_store needs a native clang vector type,
// not HIP's float4 class -> use ext_vector_type(4).

#define IN_F 8192
#define OUT_F 8192
#define BLOCK 256
#define WAVE_ITERS (IN_F / 4 / 64)   // 32 float4 per lane per row

typedef float vfloat4 __attribute__((ext_vector_type(4)));

__global__ __launch_bounds__(BLOCK) void snn_wave_fused_kernel(
    const vfloat4* __restrict__ x4,    // spike_input as float4 [IN_F/4]
    const float* __restrict__ syn,     // synapse_states [OUT_F, IN_F]
    const float* __restrict__ mem,     // membrane_potential [OUT_F]
    const float* __restrict__ thr,     // adaptive_threshold [OUT_F]
    const float* __restrict__ trace,   // eligibility_trace [OUT_F, IN_F]
    const float* __restrict__ refr,    // refractory_period [OUT_F]
    float* __restrict__ out_spikes,
    float* __restrict__ out_mem,
    float* __restrict__ out_trace,
    float* __restrict__ out_refr)
{
    const int wave = threadIdx.x >> 6;
    const int lane = threadIdx.x & 63;
    const int row  = (blockIdx.x << 2) + wave;

    const vfloat4* __restrict__ syn4 =
        (const vfloat4*)(syn + (size_t)row * IN_F);
    const vfloat4* __restrict__ tr4 =
        (const vfloat4*)(trace + (size_t)row * IN_F);
    vfloat4* __restrict__ otr4 = (vfloat4*)(out_trace + (size_t)row * IN_F);

    // Phase 1: current = dot((syn_row > 50), x). Pure read stream.
    float acc = 0.0f;
    #pragma unroll 8
    for (int it = 0; it < WAVE_ITERS; ++it) {
        const int idx = (it << 6) + lane;
        const vfloat4 s  = syn4[idx];
        const vfloat4 xv = x4[idx];     // 32 KB total: L1-resident
        acc += (s.x > 50.0f) ? xv.x : 0.0f;
        acc += (s.y > 50.0f) ? xv.y : 0.0f;
        acc += (s.z > 50.0f) ? xv.z : 0.0f;
        acc += (s.w > 50.0f) ? xv.w : 0.0f;
    }
    // Wave-local reduction; no LDS, no barrier.
    #pragma unroll
    for (int off = 32; off > 0; off >>= 1) {
        acc += __shfl_down(acc, off, 64);
    }
    const float current = __shfl(acc, 0, 64);

    // Phase 2: LIF scalars (row-uniform).
    const float r = refr[row];
    const float v = mem[row] * 0.5f + current * (1.0f - r * 0.5f);
    const float spike = (v >= thr[row]) ? 1.0f : 0.0f;
    if (lane == 0) {
        out_spikes[row] = spike;
        out_mem[row]    = v * (1.0f - spike);
        out_refr[row]   = fminf(fmaxf(r + spike - 0.1f, 0.0f), 1.0f);
    }

    // Phase 3: trace row read-modify-write stream.
    #pragma unroll 8
    for (int it = 0; it < WAVE_ITERS; ++it) {
        const int idx = (it << 6) + lane;
        const vfloat4 t  = tr4[idx];
        const vfloat4 xv = x4[idx];
        vfloat4 o;
        o.x = fminf(fmaxf(t.x * 0.8f + spike * xv.x, 0.0f), 5.0f);
        o.y = fminf(fmaxf(t.y * 0.8f + spike * xv.y, 0.0f), 5.0f);
        o.z = fminf(fmaxf(t.z * 0.8f + spike * xv.z, 0.0f), 5.0f);
        o.w = fminf(fmaxf(t.w * 0.8f + spike * xv.w, 0.0f), 5.0f);
        __builtin_nontemporal_store(o, &otr4[idx]);
    }
}

extern "C" void kernel_launch(void* const* d_in, const int* in_sizes, int n_in,
                              void* d_out, int out_size, void* d_ws, size_t ws_size,
                              hipStream_t stream) {
    const float* x_in  = (const float*)d_in[0];  // spike_input
    const float* syn   = (const float*)d_in[1];  // synapse_states
    const float* mem   = (const float*)d_in[2];  // membrane_potential
    const float* thr   = (const float*)d_in[3];  // adaptive_threshold
    const float* trace = (const float*)d_in[4];  // eligibility_trace
    const float* refr  = (const float*)d_in[5];  // refractory_period

    float* out = (float*)d_out;
    float* out_spikes = out;                                     // [8192]
    float* out_mem    = out + OUT_F;                             // [8192]
    float* out_trace  = out + 2 * OUT_F;                         // [8192^2]
    float* out_refr   = out + 2 * OUT_F + (size_t)OUT_F * IN_F;  // [8192]

    snn_wave_fused_kernel<<<OUT_F / 4, BLOCK, 0, stream>>>(
        (const vfloat4*)x_in, syn, mem, thr, trace, refr,
        out_spikes, out_mem, out_trace, out_refr);
}